// Round 16
// baseline (796.870 us; speedup 1.0000x reference)
//
#include <hip/hip_runtime.h>
#include <stdint.h>

// LSTM B=256,T=2048,D=U=64 fp32. Grid 128 WGs x 512 thr (8 waves).
// R15 (576us) is latency-bound: ~450cyc serial chain/step, SIMDs idle
// during every latency segment (1 wave/SIMD). R16: TWO batches per WG in
// SEPARATE wave-quads -> 2 waves/SIMD; the quads' chains interleave on the
// SIMDs (MFMA/LDS/transcendental latency of batch A hidden under batch B's
// issue). Waves 0-3 = batch A running EXACTLY the R15 step (proven); waves
// 4-7 = batch B, disjoint LDS (own sH/sXZ). One lgkm-only barrier per step
// syncs both quads (identical per-wave work -> minimal skew).
// NOTE vs failed R12: R12 serialized both batches INSIDE one wave (chain
// work doubled, replay-diverged); here each wave touches ONE batch only.
// k-map f(g,e)=g*8+e on BOTH A and B; C/D layout m89; replicated-A h-MFMA
// with persistent zero-C; xz per chunk via MFMA rows=timesteps.

#define T_STEPS 2048
#define DIM     64
#define GATES   256
#define CHUNK   16
#define NCHUNK  (T_STEPS / CHUNK)

typedef _Float16 f16;
typedef _Float16 f16x8 __attribute__((ext_vector_type(8)));
typedef float    f32x4 __attribute__((ext_vector_type(4)));

__device__ __forceinline__ void sync_lds() {
    __builtin_amdgcn_sched_barrier(0);
    asm volatile("s_waitcnt lgkmcnt(0)" ::: "memory");
    __builtin_amdgcn_sched_barrier(0);
    __builtin_amdgcn_s_barrier();
    __builtin_amdgcn_sched_barrier(0);
}

__device__ __forceinline__ float sigm(float z) {
    return __builtin_amdgcn_rcpf(1.f + __expf(-z));
}

#define MFMA16(A, B, C) __builtin_amdgcn_mfma_f32_16x16x32_f16(A, B, C, 0, 0, 0)

__device__ __forceinline__ void pack8(f16x8& d, const float4& a, const float4& b) {
    d[0]=(f16)a.x; d[1]=(f16)a.y; d[2]=(f16)a.z; d[3]=(f16)a.w;
    d[4]=(f16)b.x; d[5]=(f16)b.y; d[6]=(f16)b.z; d[7]=(f16)b.w;
}

__global__ __launch_bounds__(512, 1)
void lstm_r16_kernel(const float* __restrict__ x,
                     const float* __restrict__ Wx,
                     const float* __restrict__ Wh,
                     const float* __restrict__ bias,
                     float* __restrict__ out)
{
    __shared__ __align__(16) f16   sH[2][2][64];             // [half][pb][u]
    __shared__ __align__(16) float sXZ[2][4][CHUNK][16][4];  // [half][wave]..

    const int tid  = threadIdx.x;
    const int half = tid >> 8;       // 0 = batch A quad, 1 = batch B quad
    const int lane = tid & 63;
    const int w    = (tid >> 6) & 3; // wave within quad -> units w*16..+16
    const int j    = lane & 15;      // col-in-tile (B,D) / row (A, xz MFMA)
    const int g    = lane >> 4;      // k-group: k = ks*32 + g*8 + e
    const int u    = w * 16 + j;     // unit

    const int batch = blockIdx.x * 2 + half;
    const float* xb = x + (size_t)batch * T_STEPS * DIM;
    float* ob = out + (size_t)batch * T_STEPS * (2 * DIM);

    // ---- persistent B fragments: col = q*64 + u, k = ks*32 + g*8 + e ----
    f16x8 Bh[4][2], Bx[4][2];
    f32x4 bias4[4];
#pragma unroll
    for (int q = 0; q < 4; ++q) {
        const int col = q * 64 + u;
        const float bb = bias[col];
        bias4[q][0] = bb; bias4[q][1] = bb; bias4[q][2] = bb; bias4[q][3] = bb;
#pragma unroll
        for (int ks = 0; ks < 2; ++ks)
#pragma unroll
            for (int e = 0; e < 8; ++e) {
                const int k = ks * 32 + g * 8 + e;
                Bh[q][ks][e] = (f16)Wh[k * GATES + col];
                Bx[q][ks][e] = (f16)Wx[k * GATES + col];
            }
    }
    const f32x4 zero4 = {0.f, 0.f, 0.f, 0.f};

    {
        const int tq = tid & 255;
        if (tq < 128) sH[half][tq >> 6][tq & 63] = (f16)0.f;
    }

    // ---- prefetch x chunk 0: A row = ts = j, feats g*8.. ----
    float4 x0, x1, x2, x3;
    {
        const float* xr = xb + (size_t)j * DIM + g * 8;
        x0 = *(const float4*)(xr);      x1 = *(const float4*)(xr + 4);
        x2 = *(const float4*)(xr + 32); x3 = *(const float4*)(xr + 36);
    }

    float c = 0.f;   // replicated: every lane-group's lane j holds c[u]
    __syncthreads();

#pragma unroll 1
    for (int n = 0; n < NCHUNK; ++n) {
        // ---- xz chunk: z[q] = bias + X_chunk @ Wx (rows = 16 ts) ----
        f16x8 ax0, ax1;
        pack8(ax0, x0, x1); pack8(ax1, x2, x3);
        f32x4 z0 = MFMA16(ax0, Bx[0][0], bias4[0]); z0 = MFMA16(ax1, Bx[0][1], z0);
        f32x4 z1 = MFMA16(ax0, Bx[1][0], bias4[1]); z1 = MFMA16(ax1, Bx[1][1], z1);
        f32x4 z2 = MFMA16(ax0, Bx[2][0], bias4[2]); z2 = MFMA16(ax1, Bx[2][1], z2);
        f32x4 z3 = MFMA16(ax0, Bx[3][0], bias4[3]); z3 = MFMA16(ax1, Bx[3][1], z3);
        // scatter to wave-private sXZ: row = 4g+r (D-layout), unit j
#pragma unroll
        for (int r = 0; r < 4; ++r) {
            float4 v = {z0[r], z1[r], z2[r], z3[r]};
            *(float4*)&sXZ[half][w][4 * g + r][j][0] = v;
        }
        // s=0 xz read: DS in-wave program order -> consistent, no drain
        float4 xzv = *(const float4*)&sXZ[half][w][0][j][0];

        // prefetch next chunk's x (returns during the 16 steps below)
        if (n + 1 < NCHUNK) {
            const float* xr = xb + ((size_t)(n + 1) * CHUNK + j) * DIM + g * 8;
            x0 = *(const float4*)(xr);      x1 = *(const float4*)(xr + 4);
            x2 = *(const float4*)(xr + 32); x3 = *(const float4*)(xr + 36);
        }

        float* obn = ob + (size_t)n * CHUNK * 128;

#pragma unroll
        for (int s = 0; s < CHUNK; ++s) {
            const int pb = s & 1;
            // A-reads FIRST post-barrier (the only LDS on the critical path)
            f16x8 A0 = *(const f16x8*)&sH[half][pb][g * 8];
            f16x8 A1 = *(const f16x8*)&sH[half][pb][32 + g * 8];

            f32x4 h0 = MFMA16(A0, Bh[0][0], zero4); h0 = MFMA16(A1, Bh[0][1], h0);
            f32x4 h1 = MFMA16(A0, Bh[1][0], zero4); h1 = MFMA16(A1, Bh[1][1], h1);
            f32x4 h2 = MFMA16(A0, Bh[2][0], zero4); h2 = MFMA16(A1, Bh[2][1], h2);
            f32x4 h3 = MFMA16(A0, Bh[3][0], zero4); h3 = MFMA16(A1, Bh[3][1], h3);

            float zi = h0[0] + xzv.x, zf = h1[0] + xzv.y;
            float zg = h2[0] + xzv.z, zo = h3[0] + xzv.w;
            float gi = sigm(zi), gf = sigm(zf), go = sigm(zo);
            float gg = fmaf(2.f, sigm(zg + zg), -1.f);
            c = fmaf(gf, c, gi * gg);
            float e2 = __expf(-2.f * fabsf(c));
            float th = copysignf(
                fmaf(-2.f, e2 * __builtin_amdgcn_rcpf(1.f + e2), 1.f), c);
            float hh = go * th;

            // next step's xz prefetch (wave-private, stable; s=15 discarded)
            float4 xzn = *(const float4*)&sXZ[half][w][(s + 1) & 15][j][0];

            if (g == 2)      sH[half][pb ^ 1][u] = (f16)hh;  // next-step h
            else if (g == 0) obn[s * 128 + u]      = c;      // cell out
            else if (g == 1) obn[s * 128 + 64 + u] = hh;     // hidden out
            sync_lds();
            xzv = xzn;
        }
    }
}

extern "C" void kernel_launch(void* const* d_in, const int* in_sizes, int n_in,
                              void* d_out, int out_size, void* d_ws, size_t ws_size,
                              hipStream_t stream) {
    const float* x  = (const float*)d_in[0];
    const float* Wx = (const float*)d_in[1];
    const float* Wh = (const float*)d_in[2];
    const float* b  = (const float*)d_in[3];
    float* out = (float*)d_out;

    hipLaunchKernelGGL(lstm_r16_kernel, dim3(128), dim3(512), 0, stream,
                       x, Wx, Wh, b, out);
}

// Round 17
// 595.576 us; speedup vs baseline: 1.3380x; 1.3380x over previous
//
#include <hip/hip_runtime.h>
#include <stdint.h>

// LSTM B=256,T=2048,D=U=64 fp32. Grid 256 WGs (1 batch) x 512 thr (8 waves).
// R17 = R15 consumer step (proven, 576us) + producer/consumer wave split:
//  waves 0-3 (consumers): pure recurrence, NOTHING at chunk boundaries
//    (no Bx/bias/x-loads/xz-MFMAs in their path anymore).
//  waves 4-7 (producers): compute chunk n+1's xz = bias + X@Wx into
//    double-buffered sXZ, work spread across the 16 barrier slots
//    (slots 0-3: MFMA pairs, 4-7: scatter, 8-11: x loads chunk n+2,
//     12-13: f16 pack). Light per slot -> fills consumer latency bubbles
//    (R16 measured 2-waves/SIMD hides ~200cyc/step of the 675cyc chain).
// Handoff safety by barrier ordering: producer scatter of buf nb done by
// slot-7 barrier; consumer first reads buf nb at slot 15. Producer reuses
// buf cb only in chunk n+1 (consumer's last cb read = slot 14 of chunk n).
// Structure/math otherwise identical to R15: replicated-A h-MFMA with
// persistent zero-C, one lgkm-only barrier per step, vmcnt never drained.
// k-map f(g,e)=g*8+e on BOTH A and B; C/D layout m89-verified.

#define T_STEPS 2048
#define DIM     64
#define GATES   256
#define CHUNK   16
#define NCHUNK  (T_STEPS / CHUNK)

typedef _Float16 f16;
typedef _Float16 f16x8 __attribute__((ext_vector_type(8)));
typedef float    f32x4 __attribute__((ext_vector_type(4)));

__device__ __forceinline__ void sync_lds() {
    __builtin_amdgcn_sched_barrier(0);
    asm volatile("s_waitcnt lgkmcnt(0)" ::: "memory");
    __builtin_amdgcn_sched_barrier(0);
    __builtin_amdgcn_s_barrier();
    __builtin_amdgcn_sched_barrier(0);
}

__device__ __forceinline__ float sigm(float z) {
    return __builtin_amdgcn_rcpf(1.f + __expf(-z));
}

#define MFMA16(A, B, C) __builtin_amdgcn_mfma_f32_16x16x32_f16(A, B, C, 0, 0, 0)

__device__ __forceinline__ void pack8(f16x8& d, const float4& a, const float4& b) {
    d[0]=(f16)a.x; d[1]=(f16)a.y; d[2]=(f16)a.z; d[3]=(f16)a.w;
    d[4]=(f16)b.x; d[5]=(f16)b.y; d[6]=(f16)b.z; d[7]=(f16)b.w;
}

__global__ __launch_bounds__(512, 1)
void lstm_r17_kernel(const float* __restrict__ x,
                     const float* __restrict__ Wx,
                     const float* __restrict__ Wh,
                     const float* __restrict__ bias,
                     float* __restrict__ out)
{
    __shared__ __align__(16) f16   sH[2][64];                // h dbuf (f16)
    __shared__ __align__(16) float sXZ[2][4][CHUNK][16][4];  // dbuf xz

    const int tid  = threadIdx.x;
    const int lane = tid & 63;
    const int wq   = tid >> 6;       // 0..7
    const bool consumer = (wq < 4);
    const int w    = wq & 3;         // unit block (both roles)
    const int j    = lane & 15;
    const int g    = lane >> 4;      // k-group: k = ks*32 + g*8 + e
    const int u    = w * 16 + j;

    const int batch = blockIdx.x;
    const float* xb = x + (size_t)batch * T_STEPS * DIM;
    float* ob = out + (size_t)batch * T_STEPS * (2 * DIM);

    // ---- weight fragments: consumer=Wh, producer=Wx. col = q*64+u ----
    const float* Wsrc = consumer ? Wh : Wx;
    f16x8 Bw[4][2];
    f32x4 bias4[4];
#pragma unroll
    for (int q = 0; q < 4; ++q) {
        const int col = q * 64 + u;
        const float bb = bias[col];
        bias4[q][0] = bb; bias4[q][1] = bb; bias4[q][2] = bb; bias4[q][3] = bb;
#pragma unroll
        for (int ks = 0; ks < 2; ++ks)
#pragma unroll
            for (int e = 0; e < 8; ++e) {
                const int k = ks * 32 + g * 8 + e;
                Bw[q][ks][e] = (f16)Wsrc[k * GATES + col];
            }
    }
    const f32x4 zero4 = {0.f, 0.f, 0.f, 0.f};

    if (tid < 128) sH[tid >> 6][tid & 63] = (f16)0.f;

    // ---- producer prologue: xz chunk 0 -> sXZ[0]; ax packed for chunk 1 ---
    float4 x0, x1, x2, x3;
    f16x8 axc0, axc1;
    f32x4 p0, p1, p2, p3;
    if (!consumer) {
        const float* xr = xb + (size_t)j * DIM + g * 8;
        x0 = *(const float4*)(xr);      x1 = *(const float4*)(xr + 4);
        x2 = *(const float4*)(xr + 32); x3 = *(const float4*)(xr + 36);
        pack8(axc0, x0, x1); pack8(axc1, x2, x3);
        p0 = MFMA16(axc0, Bw[0][0], bias4[0]); p0 = MFMA16(axc1, Bw[0][1], p0);
        p1 = MFMA16(axc0, Bw[1][0], bias4[1]); p1 = MFMA16(axc1, Bw[1][1], p1);
        p2 = MFMA16(axc0, Bw[2][0], bias4[2]); p2 = MFMA16(axc1, Bw[2][1], p2);
        p3 = MFMA16(axc0, Bw[3][0], bias4[3]); p3 = MFMA16(axc1, Bw[3][1], p3);
#pragma unroll
        for (int r = 0; r < 4; ++r) {
            float4 v = {p0[r], p1[r], p2[r], p3[r]};
            *(float4*)&sXZ[0][w][4 * g + r][j][0] = v;
        }
        // x for chunk 1, packed -> used during chunk 0 slots
        const float* xr1 = xb + ((size_t)CHUNK + j) * DIM + g * 8;
        x0 = *(const float4*)(xr1);      x1 = *(const float4*)(xr1 + 4);
        x2 = *(const float4*)(xr1 + 32); x3 = *(const float4*)(xr1 + 36);
        pack8(axc0, x0, x1); pack8(axc1, x2, x3);
    }
    __syncthreads();

    float c = 0.f;   // replicated: every lane-group's lane j holds c[u]
    float4 xzv;
    if (consumer) xzv = *(const float4*)&sXZ[0][w][0][j][0];

#pragma unroll 1
    for (int n = 0; n < NCHUNK; ++n) {
        const int cb = n & 1, nb = cb ^ 1;
        float* obn = ob + (size_t)n * CHUNK * 128;
        const bool mk1 = (n + 1 < NCHUNK);   // produce chunk n+1
        const bool mk2 = (n + 2 < NCHUNK);   // stage x for chunk n+2

#pragma unroll
        for (int s = 0; s < CHUNK; ++s) {
            const int pb = s & 1;
            if (consumer) {
                // A-reads FIRST post-barrier (only LDS on the critical path)
                f16x8 A0 = *(const f16x8*)&sH[pb][g * 8];
                f16x8 A1 = *(const f16x8*)&sH[pb][32 + g * 8];

                f32x4 h0 = MFMA16(A0, Bw[0][0], zero4); h0 = MFMA16(A1, Bw[0][1], h0);
                f32x4 h1 = MFMA16(A0, Bw[1][0], zero4); h1 = MFMA16(A1, Bw[1][1], h1);
                f32x4 h2 = MFMA16(A0, Bw[2][0], zero4); h2 = MFMA16(A1, Bw[2][1], h2);
                f32x4 h3 = MFMA16(A0, Bw[3][0], zero4); h3 = MFMA16(A1, Bw[3][1], h3);

                float zi = h0[0] + xzv.x, zf = h1[0] + xzv.y;
                float zg = h2[0] + xzv.z, zo = h3[0] + xzv.w;
                float gi = sigm(zi), gf = sigm(zf), go = sigm(zo);
                float gg = fmaf(2.f, sigm(zg + zg), -1.f);
                c = fmaf(gf, c, gi * gg);
                float e2 = __expf(-2.f * fabsf(c));
                float th = copysignf(
                    fmaf(-2.f, e2 * __builtin_amdgcn_rcpf(1.f + e2), 1.f), c);
                float hh = go * th;

                // next step's xz prefetch (double-buffer aware; s compile-time)
                float4 xzn = (s == 15)
                    ? *(const float4*)&sXZ[nb][w][0][j][0]
                    : *(const float4*)&sXZ[cb][w][s + 1][j][0];

                if (g == 2)      sH[pb ^ 1][u] = (f16)hh;     // next-step h
                else if (g == 0) obn[s * 128 + u]      = c;   // cell out
                else if (g == 1) obn[s * 128 + 64 + u] = hh;  // hidden out
                xzv = xzn;
            } else {
                // ---- producer: chunk n+1 xz, spread across slots ----
                if (mk1) {
                    if (s == 0) { p0 = MFMA16(axc0, Bw[0][0], bias4[0]); p0 = MFMA16(axc1, Bw[0][1], p0); }
                    if (s == 1) { p1 = MFMA16(axc0, Bw[1][0], bias4[1]); p1 = MFMA16(axc1, Bw[1][1], p1); }
                    if (s == 2) { p2 = MFMA16(axc0, Bw[2][0], bias4[2]); p2 = MFMA16(axc1, Bw[2][1], p2); }
                    if (s == 3) { p3 = MFMA16(axc0, Bw[3][0], bias4[3]); p3 = MFMA16(axc1, Bw[3][1], p3); }
                    if (s >= 4 && s < 8) {
                        const int r = s - 4;
                        float4 v = {p0[r], p1[r], p2[r], p3[r]};
                        *(float4*)&sXZ[nb][w][4 * g + r][j][0] = v;
                    }
                }
                if (mk2) {
                    const float* xr = xb + ((size_t)(n + 2) * CHUNK + j) * DIM + g * 8;
                    if (s == 8)  x0 = *(const float4*)(xr);
                    if (s == 9)  x1 = *(const float4*)(xr + 4);
                    if (s == 10) x2 = *(const float4*)(xr + 32);
                    if (s == 11) x3 = *(const float4*)(xr + 36);
                    if (s == 12) pack8(axc0, x0, x1);
                    if (s == 13) pack8(axc1, x2, x3);
                }
            }
            sync_lds();
        }
    }
}

extern "C" void kernel_launch(void* const* d_in, const int* in_sizes, int n_in,
                              void* d_out, int out_size, void* d_ws, size_t ws_size,
                              hipStream_t stream) {
    const float* x  = (const float*)d_in[0];
    const float* Wx = (const float*)d_in[1];
    const float* Wh = (const float*)d_in[2];
    const float* b  = (const float*)d_in[3];
    float* out = (float*)d_out;

    hipLaunchKernelGGL(lstm_r17_kernel, dim3(256), dim3(512), 0, stream,
                       x, Wx, Wh, b, out);
}